// Round 4
// baseline (810.642 us; speedup 1.0000x reference)
//
#include <hip/hip_runtime.h>
#include <stdint.h>

typedef unsigned short ushort_t;
typedef __attribute__((ext_vector_type(8))) _Float16 half8;   // 8 fp16 = 4 VGPRs
typedef __attribute__((ext_vector_type(2))) __fp16 fp16x2;    // cvt_pkrtz result type
typedef __attribute__((ext_vector_type(4))) float f32x4;

__device__ __forceinline__ ushort_t h_bits(_Float16 h) {
    union { _Float16 h; ushort_t u; } v; v.h = h; return v.u;
}
__device__ __forceinline__ ushort_t f2h(float x) { return h_bits((_Float16)x); }

// fp16 hi/lo split of a pair via v_cvt_pkrtz (1 instr per 2 elements).
// lo = x - (float)hi is EXACT (Dekker); pair error <= ~2^-21 |x|.
__device__ __forceinline__ void split_pair(float x0, float x1, unsigned& hp, unsigned& lp) {
    fp16x2 h = __builtin_amdgcn_cvt_pkrtz(x0, x1);
    float r0 = x0 - (float)h[0];
    float r1 = x1 - (float)h[1];
    fp16x2 l = __builtin_amdgcn_cvt_pkrtz(r0, r1);
    union { fp16x2 v; unsigned u; } a, b; a.v = h; b.v = l;
    hp = a.u; lp = b.u;
}

__device__ __forceinline__ void gload_lds16(const ushort_t* g, ushort_t* l) {
    __builtin_amdgcn_global_load_lds(
        (const __attribute__((address_space(1))) void*)g,
        (__attribute__((address_space(3))) void*)l, 16, 0, 0);
}

// ---------------------------------------------------------------------------
// prep_all: ALL prep work in ONE launch (block-range dispatch; every sub-task
// uses 256-thread blocks).
//   blocks [0, 8192)        : x_pos -> cat hi/lo + pad zeroing
//   blocks [8192, 8192+1272): 5 weight transposes (tiled 32x32 via LDS)
// Weight layout: out[n*2K + k] = fp16_hi(W[k-shift][n]), out[n*2K+K+k] = lo.
// ---------------------------------------------------------------------------
__global__ void prep_all(const float* __restrict__ seqf,
                         const float* __restrict__ W1t, const float* __restrict__ W1v,
                         const float* __restrict__ W2v, const float* __restrict__ Wfp,
                         const float* __restrict__ Wfc,
                         ushort_t* __restrict__ wt1, ushort_t* __restrict__ wt2,
                         ushort_t* __restrict__ wt3, ushort_t* __restrict__ wt4,
                         ushort_t* __restrict__ wt5, ushort_t* __restrict__ cat)
{
    __shared__ float tile[32][33];
    int b = blockIdx.x;
    if (b < 8192) {
        // ---- prep_cat_pos ----
        long t = (long)b * 256 + threadIdx.x;  // M*64 threads
        long m = t >> 6; int c = (int)(t & 63);
        float x = (c < 4) ? seqf[m * 2352 + 2348 + c] : 0.f;
        _Float16 h = (_Float16)x;
        cat[m * 640 + 256 + c] = h_bits(h);           // hi section cols [256,320)
        cat[m * 640 + 576 + c] = f2h(x - (float)h);   // lo section cols [576,640)
        return;
    }
    b -= 8192;
    // ---- weight transpose tasks ----
    const float* W; ushort_t* out; int Ksrc, Nsrc, K, shift, gx;
    if (b < 40)        { W = W1t; Ksrc = 300;  Nsrc = 128; out = wt1; K = 320;  shift = 0;  gx = 10; }
    else if (b < 1096) { b -= 40;   W = W1v; Ksrc = 2048; Nsrc = 512; out = wt2; K = 2112; shift = 12; gx = 66; }
    else if (b < 1160) { b -= 1096; W = W2v; Ksrc = 512;  Nsrc = 128; out = wt3; K = 512;  shift = 0;  gx = 16; }
    else if (b < 1240) { b -= 1160; W = Wfp; Ksrc = 260;  Nsrc = 256; out = wt4; K = 320;  shift = 0;  gx = 10; }
    else               { b -= 1240; W = Wfc; Ksrc = 256;  Nsrc = 128; out = wt5; K = 256;  shift = 0;  gx = 8;  }
    const int kt = (b % gx) * 32, nt = (b / gx) * 32;
    const int tx = threadIdx.x & 31, ty = threadIdx.x >> 5;   // 32 x 8
#pragma unroll
    for (int r = ty; r < 32; r += 8) {
        int k = kt + r - shift;
        int n = nt + tx;
        tile[r][tx] = (k >= 0 && k < Ksrc && n < Nsrc) ? W[(long)k * Nsrc + n] : 0.f;
    }
    __syncthreads();
#pragma unroll
    for (int r = ty; r < 32; r += 8) {
        int n = nt + r, k = kt + tx;
        if (n < Nsrc && k < K) {
            float w = tile[tx][r];
            _Float16 h = (_Float16)w;
            out[(long)n * 2 * K + k]     = h_bits(h);
            out[(long)n * 2 * K + K + k] = f2h(w - (float)h);
        }
    }
}

// ===========================================================================
// GEMM common: 128x128 tile, BK=64, 4 waves, XOR LDS swizzle on B,
// 3 MFMA passes (Ah·Bh + Al·Bh + Ah·Bl, drop Al·Bl ~2^-21).
// ===========================================================================

// --- Variant A: A is fp32 (seq). A path is global->reg gather (128B-coalesced
// per 16 lanes) + cvt_pkrtz split DIRECTLY into MFMA fragment registers — no
// A LDS at all (LDS 32KB = B only; removes 8 ds_write + 24 ds_read per step).
// Fused dual-GEMM launch: blocks [0,nb1) use param set 1, rest use set 2.
__global__ __launch_bounds__(256, 2)
void gemm_af32(const float* __restrict__ Af, long ldaf, unsigned long long a_maxf,
               int nb1,
               long aoff1, const ushort_t* __restrict__ Bt1, int K1, int ntiles1,
               const float* __restrict__ bias1, ushort_t* __restrict__ out1,
               int ostride1, int hi1, int lo1,
               long aoff2, const ushort_t* __restrict__ Bt2, int K2, int ntiles2,
               const float* __restrict__ bias2, ushort_t* __restrict__ out2,
               int ostride2, int hi2, int lo2)
{
    __shared__ __align__(16) ushort_t Bh[128 * 64];
    __shared__ __align__(16) ushort_t Bl[128 * 64];

    // param-set select (wave-uniform branch by block range)
    long aoff; const ushort_t* Bt; int K, ntiles; const float* bias;
    ushort_t* outb; int ostride, hi_off, lo_off, b;
    if (blockIdx.x < (unsigned)nb1) {
        b = blockIdx.x;
        aoff = aoff1; Bt = Bt1; K = K1; ntiles = ntiles1; bias = bias1;
        outb = out1; ostride = ostride1; hi_off = hi1; lo_off = lo1;
    } else {
        b = blockIdx.x - nb1;
        aoff = aoff2; Bt = Bt2; K = K2; ntiles = ntiles2; bias = bias2;
        outb = out2; ostride = ostride2; hi_off = hi2; lo_off = lo2;
    }

    const int tt = b >> 3;
    const int bx = tt % ntiles;
    const int by = (tt / ntiles) * 8 + (b & 7);

    const int t  = threadIdx.x;
    const int w  = t >> 6, l = t & 63;
    const int wm = w >> 1, wn = w & 1;
    const long m0 = (long)by * 128;
    const int  n0 = bx * 128;
    const long K2s = 2L * K;

    // B staging (global_load_lds, gather-side XOR): chunk c=w*4+i, lane -> row c*8+(l>>3)
    const int lr = l >> 3;
    const int kbg = (l & 7) ^ lr;
    long rowB[4];
#pragma unroll
    for (int i = 0; i < 4; ++i) {
        int c = w * 4 + i;
        rowB[i] = (long)(n0 + c * 8 + lr) * K2s + kbg * 8;
    }

    const int col = l & 15, quad = l >> 4;

    // A gather bases: row m = m0 + wm*64 + i*16 + col; k-slice = (kk*4+quad)*8
    unsigned long long abase[4];
#pragma unroll
    for (int i = 0; i < 4; ++i)
        abase[i] = (unsigned long long)((m0 + wm * 64 + i * 16 + col) * ldaf + aoff);

    f32x4 acc[4][4];
#pragma unroll
    for (int i = 0; i < 4; ++i)
#pragma unroll
        for (int j = 0; j < 4; ++j) acc[i][j] = (f32x4){0.f, 0.f, 0.f, 0.f};

    for (int k0 = 0; k0 < K; k0 += 64) {
        __syncthreads();            // prev compute done before B LDS overwrite
#pragma unroll
        for (int i = 0; i < 4; ++i) {
            const int cb = (w * 4 + i) * 512;
            gload_lds16(Bt + rowB[i] + k0, &Bh[cb]);       // async B while we gather/convert A
            gload_lds16(Bt + rowB[i] + K + k0, &Bl[cb]);
        }
        // A: global -> regs -> fp16 hi/lo fragments (no LDS)
        half8 ah[4][2], al[4][2];
#pragma unroll
        for (int i = 0; i < 4; ++i) {
#pragma unroll
            for (int kk = 0; kk < 2; ++kk) {
                unsigned long long g = abase[i] + (unsigned long long)(k0 + (kk * 4 + quad) * 8);
                if (g > a_maxf) g = a_maxf;    // tail overrun -> valid addr (zero weights)
                float4 v0 = *(const float4*)(Af + g);
                float4 v1 = *(const float4*)(Af + g + 4);
                union { unsigned u[4]; half8 h; } H, L;
                split_pair(v0.x, v0.y, H.u[0], L.u[0]);
                split_pair(v0.z, v0.w, H.u[1], L.u[1]);
                split_pair(v1.x, v1.y, H.u[2], L.u[2]);
                split_pair(v1.z, v1.w, H.u[3], L.u[3]);
                ah[i][kk] = H.h; al[i][kk] = L.h;
            }
        }
        __syncthreads();            // drains vmcnt: B staging visible

#pragma unroll
        for (int p = 0; p < 3; ++p) {
            const ushort_t* Bsrc = (p == 2) ? Bl : Bh;
#pragma unroll
            for (int kk = 0; kk < 2; ++kk) {
                half8 bb[4];
#pragma unroll
                for (int j = 0; j < 4; ++j) {
                    int n = wn * 64 + j * 16 + col;
                    int kbs = (kk * 4 + quad) ^ (n & 7);
                    bb[j] = *(const half8*)&Bsrc[n * 64 + kbs * 8];
                }
#pragma unroll
                for (int i = 0; i < 4; ++i)
#pragma unroll
                    for (int j = 0; j < 4; ++j)
                        acc[i][j] = __builtin_amdgcn_mfma_f32_16x16x32_f16(
                            (p == 1) ? al[i][kk] : ah[i][kk], bb[j], acc[i][j], 0, 0, 0);
            }
        }
    }

    // epilogue: relu -> hi/lo fp16 (C/D map col=lane&15, row=quad*4+reg)
#pragma unroll
    for (int j = 0; j < 4; ++j) {
        int n = n0 + wn * 64 + j * 16 + col;
        float bv = bias[n];
#pragma unroll
        for (int i = 0; i < 4; ++i) {
#pragma unroll
            for (int r = 0; r < 4; ++r) {
                long m = m0 + wm * 64 + i * 16 + quad * 4 + r;
                float y = fmaxf(acc[i][j][r] + bv, 0.f);
                _Float16 h = (_Float16)y;
                outb[m * (long)ostride + hi_off + n] = h_bits(h);
                outb[m * (long)ostride + lo_off + n] = f2h(y - (float)h);
            }
        }
    }
}

// --- Variant B: A is fp16 hi/lo (activations), global_load_lds staging. Relu.
__global__ __launch_bounds__(256, 2)
void gemm_bt(const ushort_t* __restrict__ A, long lda, long aoff_hi, long aoff_lo,
             unsigned long long a_max,
             const ushort_t* __restrict__ Bt, int K, int ntiles,
             const float* __restrict__ bias,
             ushort_t* __restrict__ outb, int ostride, int hi_off, int lo_off)
{
    __shared__ __align__(16) ushort_t Ah[128 * 64];
    __shared__ __align__(16) ushort_t Al[128 * 64];
    __shared__ __align__(16) ushort_t Bh[128 * 64];
    __shared__ __align__(16) ushort_t Bl[128 * 64];

    const int b = blockIdx.x;
    const int tt = b >> 3;
    const int bx = tt % ntiles;
    const int by = (tt / ntiles) * 8 + (b & 7);

    const int t  = threadIdx.x;
    const int w  = t >> 6, l = t & 63;
    const int wm = w >> 1, wn = w & 1;
    const long m0 = (long)by * 128;
    const int  n0 = bx * 128;
    const long K2 = 2L * K;

    const int lr = l >> 3;
    const int kbg = (l & 7) ^ lr;
    unsigned long long rowA[4]; long rowB[4];
#pragma unroll
    for (int i = 0; i < 4; ++i) {
        int c = w * 4 + i;
        rowA[i] = (unsigned long long)((m0 + c * 8 + lr) * lda + kbg * 8);
        rowB[i] = (long)(n0 + c * 8 + lr) * K2 + kbg * 8;
    }

    f32x4 acc[4][4];
#pragma unroll
    for (int i = 0; i < 4; ++i)
#pragma unroll
        for (int j = 0; j < 4; ++j) acc[i][j] = (f32x4){0.f, 0.f, 0.f, 0.f};

    const int col = l & 15, quad = l >> 4;

    for (int k0 = 0; k0 < K; k0 += 64) {
        __syncthreads();
#pragma unroll
        for (int i = 0; i < 4; ++i) {
            const int cb = (w * 4 + i) * 512;
            unsigned long long ah = rowA[i] + (unsigned long long)(aoff_hi + k0);
            unsigned long long al = rowA[i] + (unsigned long long)(aoff_lo + k0);
            if (ah > a_max) ah = a_max;
            if (al > a_max) al = a_max;
            gload_lds16(A + ah, &Ah[cb]);
            gload_lds16(A + al, &Al[cb]);
            gload_lds16(Bt + rowB[i] + k0, &Bh[cb]);
            gload_lds16(Bt + rowB[i] + K + k0, &Bl[cb]);
        }
        __syncthreads();

#pragma unroll
        for (int p = 0; p < 3; ++p) {
            const ushort_t* Asrc = (p == 1) ? Al : Ah;
            const ushort_t* Bsrc = (p == 2) ? Bl : Bh;
#pragma unroll
            for (int kk = 0; kk < 2; ++kk) {
                half8 a[4], bb[4];
#pragma unroll
                for (int i = 0; i < 4; ++i) {
                    int m = wm * 64 + i * 16 + col;
                    int kbs = (kk * 4 + quad) ^ (m & 7);
                    a[i] = *(const half8*)&Asrc[m * 64 + kbs * 8];
                }
#pragma unroll
                for (int j = 0; j < 4; ++j) {
                    int n = wn * 64 + j * 16 + col;
                    int kbs = (kk * 4 + quad) ^ (n & 7);
                    bb[j] = *(const half8*)&Bsrc[n * 64 + kbs * 8];
                }
#pragma unroll
                for (int i = 0; i < 4; ++i)
#pragma unroll
                    for (int j = 0; j < 4; ++j)
                        acc[i][j] = __builtin_amdgcn_mfma_f32_16x16x32_f16(a[i], bb[j], acc[i][j], 0, 0, 0);
            }
        }
    }

#pragma unroll
    for (int j = 0; j < 4; ++j) {
        int n = n0 + wn * 64 + j * 16 + col;
        float bv = bias[n];
#pragma unroll
        for (int i = 0; i < 4; ++i) {
#pragma unroll
            for (int r = 0; r < 4; ++r) {
                long m = m0 + wm * 64 + i * 16 + quad * 4 + r;
                float y = fmaxf(acc[i][j][r] + bv, 0.f);
                _Float16 h = (_Float16)y;
                outb[m * (long)ostride + hi_off + n] = h_bits(h);
                outb[m * (long)ostride + lo_off + n] = f2h(y - (float)h);
            }
        }
    }
}

// --- Variant C: GEMM5 + sinkhorn fused. One block = one 128x128 M-tile = one
// batch matrix. K-loop as variant B; epilogue writes tanh(z) into the dead
// staging LDS (swizzled col (n+m)&127 -> conflict-free row AND col reads),
// builds register K = exp(z*10), runs 20 sinkhorn iterations on u/v in LDS.
__global__ __launch_bounds__(256, 1)
void gemm_sink(const ushort_t* __restrict__ A, long lda, long aoff_hi, long aoff_lo,
               unsigned long long a_max,
               const ushort_t* __restrict__ Bt, int K,
               const float* __restrict__ bias,
               float* __restrict__ out)
{
    __shared__ __align__(16) unsigned char smem[65536];
    ushort_t* Ah = (ushort_t*)smem;              // 16 KB each
    ushort_t* Al = (ushort_t*)(smem + 16384);
    ushort_t* Bh = (ushort_t*)(smem + 32768);
    ushort_t* Bl = (ushort_t*)(smem + 49152);

    const int b = blockIdx.x;                    // batch index (identity swizzle)
    const int t  = threadIdx.x;
    const int w  = t >> 6, l = t & 63;
    const int wm = w >> 1, wn = w & 1;
    const long m0 = (long)b * 128;
    const long K2 = 2L * K;

    const int lr = l >> 3;
    const int kbg = (l & 7) ^ lr;
    unsigned long long rowA[4]; long rowB[4];
#pragma unroll
    for (int i = 0; i < 4; ++i) {
        int c = w * 4 + i;
        rowA[i] = (unsigned long long)((m0 + c * 8 + lr) * lda + kbg * 8);
        rowB[i] = (long)(c * 8 + lr) * K2 + kbg * 8;
    }

    f32x4 acc[4][4];
#pragma unroll
    for (int i = 0; i < 4; ++i)
#pragma unroll
        for (int j = 0; j < 4; ++j) acc[i][j] = (f32x4){0.f, 0.f, 0.f, 0.f};

    const int col = l & 15, quad = l >> 4;

    for (int k0 = 0; k0 < K; k0 += 64) {
        __syncthreads();
#pragma unroll
        for (int i = 0; i < 4; ++i) {
            const int cb = (w * 4 + i) * 512;
            unsigned long long ah = rowA[i] + (unsigned long long)(aoff_hi + k0);
            unsigned long long al = rowA[i] + (unsigned long long)(aoff_lo + k0);
            if (ah > a_max) ah = a_max;
            if (al > a_max) al = a_max;
            gload_lds16(A + ah, &Ah[cb]);
            gload_lds16(A + al, &Al[cb]);
            gload_lds16(Bt + rowB[i] + k0, &Bh[cb]);
            gload_lds16(Bt + rowB[i] + K + k0, &Bl[cb]);
        }
        __syncthreads();
#pragma unroll
        for (int p = 0; p < 3; ++p) {
            const ushort_t* Asrc = (p == 1) ? Al : Ah;
            const ushort_t* Bsrc = (p == 2) ? Bl : Bh;
#pragma unroll
            for (int kk = 0; kk < 2; ++kk) {
                half8 a[4], bb[4];
#pragma unroll
                for (int i = 0; i < 4; ++i) {
                    int m = wm * 64 + i * 16 + col;
                    int kbs = (kk * 4 + quad) ^ (m & 7);
                    a[i] = *(const half8*)&Asrc[m * 64 + kbs * 8];
                }
#pragma unroll
                for (int j = 0; j < 4; ++j) {
                    int n = wn * 64 + j * 16 + col;
                    int kbs = (kk * 4 + quad) ^ (n & 7);
                    bb[j] = *(const half8*)&Bsrc[n * 64 + kbs * 8];
                }
#pragma unroll
                for (int i = 0; i < 4; ++i)
#pragma unroll
                    for (int j = 0; j < 4; ++j)
                        acc[i][j] = __builtin_amdgcn_mfma_f32_16x16x32_f16(a[i], bb[j], acc[i][j], 0, 0, 0);
            }
        }
    }

    // ---- epilogue: z = tanh(acc + bias) -> swizzled LDS ----
    __syncthreads();                       // LDS dead; reuse as z tile
    float* zs = (float*)smem;              // 128x128 fp32, col stored at (n+m)&127
#pragma unroll
    for (int j = 0; j < 4; ++j) {
        int n = wn * 64 + j * 16 + col;
        float bv = bias[n];
#pragma unroll
        for (int i = 0; i < 4; ++i) {
#pragma unroll
            for (int r = 0; r < 4; ++r) {
                int m = wm * 64 + i * 16 + quad * 4 + r;
                float y = acc[i][j][r] + bv;
                float e = __expf(2.f * y);             // tanh = 1 - 2/(e+1), inf-safe
                zs[m * 128 + ((n + m) & 127)] = 1.f - 2.f / (e + 1.f);
            }
        }
    }
    __syncthreads();

    // ---- sinkhorn: X = diag(u) K diag(v), K register-resident ----
    const int jc = t & 127, h = t >> 7;
    float Kc[64], Kr[64];
#pragma unroll
    for (int s = 0; s < 64; ++s) {         // column copy: K[h+2s][jc]
        int m = h + 2 * s;
        Kc[s] = __expf(zs[m * 128 + ((jc + m) & 127)] * 10.0f);
    }
#pragma unroll
    for (int s = 0; s < 64; ++s) {         // row copy: K[jc][h+2s]
        int n = h + 2 * s;
        Kr[s] = __expf(zs[jc * 128 + ((n + jc) & 127)] * 10.0f);
    }
    __syncthreads();                       // zs dead; carve u/v/P from smem
    float* P = (float*)smem;               // 256 floats
    float* u = P + 256;                    // 128
    float* v = u + 128;                    // 128
    if (t < 128) { u[t] = 1.f; v[t] = 1.f; }
    __syncthreads();

#pragma unroll 1
    for (int it = 0; it < 20; ++it) {
        float p = 0.f;
#pragma unroll
        for (int s = 0; s < 64; ++s) p += u[h + 2 * s] * Kc[s];
        P[t] = p;
        __syncthreads();
        if (t < 128) {
            float T = P[t] + P[t + 128];
            float vv = v[t];
            v[t] = vv / (1e-7f + vv * T);
        }
        __syncthreads();
        p = 0.f;
#pragma unroll
        for (int s = 0; s < 64; ++s) p += v[h + 2 * s] * Kr[s];
        P[t] = p;
        __syncthreads();
        if (t < 128) {
            float R = P[t] + P[t + 128];
            float uu = u[t];
            u[t] = uu / (1e-7f + uu * R);
        }
        __syncthreads();
    }

    const long base = m0 * 128;
#pragma unroll
    for (int s = 0; s < 64; ++s)           // out[(h+2s)*128 + jc] == t + 256s
        out[base + t + 256 * s] = u[h + 2 * s] * Kc[s] * v[jc];
}

// ---------------------------------------------------------------------------
extern "C" void kernel_launch(void* const* d_in, const int* in_sizes, int n_in,
                              void* d_out, int out_size, void* d_ws, size_t ws_size,
                              hipStream_t stream)
{
    const float* seqf = (const float*)d_in[0];
    const float* W1t = (const float*)d_in[1];
    const float* b1t = (const float*)d_in[2];
    const float* W1v = (const float*)d_in[3];
    const float* b1v = (const float*)d_in[4];
    const float* W2v = (const float*)d_in[5];
    const float* b2v = (const float*)d_in[6];
    const float* Wfp = (const float*)d_in[7];
    const float* bfp = (const float*)d_in[8];
    const float* Wfc = (const float*)d_in[9];
    const float* bfc = (const float*)d_in[10];

    char* ws = (char*)d_ws;
    size_t off = 0;
    auto alloc = [&](size_t bytes) { void* p = ws + off; off += (bytes + 255) & ~255ull; return p; };
    ushort_t* wt1 = (ushort_t*)alloc(128ull * 640 * 2);    // W1_txt^T  [h|l] K=320
    ushort_t* wt2 = (ushort_t*)alloc(512ull * 4224 * 2);   // W1_vis^T  [h|l] K=2112, shift12
    ushort_t* wt3 = (ushort_t*)alloc(128ull * 1024 * 2);   // W2_vis^T  [h|l] K=512
    ushort_t* wt4 = (ushort_t*)alloc(256ull * 640 * 2);    // W_fc_pos^T[h|l] K=320
    ushort_t* wt5 = (ushort_t*)alloc(128ull * 512 * 2);    // W_fc^T    [h|l] K=256
    ushort_t* vis = (ushort_t*)alloc(32768ull * 1024 * 2); // x_vis1 [hi(512)|lo(512)]
    ushort_t* cat = (ushort_t*)alloc(32768ull * 640 * 2);  // concat [hi(320)|lo(320)]
    ushort_t* fc  = (ushort_t*)alloc(32768ull * 512 * 2);  // fc_pos [hi(256)|lo(256)]

    // L1: all prep in one launch (8192 cat blocks + 40+1056+64+80+32 transpose)
    prep_all<<<9464, 256, 0, stream>>>(seqf, W1t, W1v, W2v, Wfp, Wfc,
                                       wt1, wt2, wt3, wt4, wt5, cat);

    const unsigned long long seq_maxf = 32768ull * 2352 - 8;   // floats

    // L2: GEMM1 (txt, K=320 -> cat[0,128)h/[320,448)l) + GEMM2 (vis1, K=2112
    // shift12 -> vis) fused into one launch: blocks [0,256) + [256,1280).
    gemm_af32<<<1280, 256, 0, stream>>>(seqf, 2352, seq_maxf, 256,
        /*set1*/ 0,   wt1, 320,  1, b1t, cat, 640, 0, 320,
        /*set2*/ 288, wt2, 2112, 4, b1v, vis, 1024, 0, 512);

    // L3: GEMM3 (vis2): A=vis, K=512 -> cat cols [128,256) hi, [448,576) lo
    gemm_bt<<<256, 256, 0, stream>>>(vis, 1024, 0, 512, 32768ull * 1024 - 8,
                                     wt3, 512, 1, b2v, cat, 640, 128, 448);
    // L4: GEMM4 (fc_pos): A=cat, K=320 -> fc hi|lo
    gemm_bt<<<512, 256, 0, stream>>>(cat, 640, 0, 320, 32768ull * 640 - 8,
                                     wt4, 320, 2, bfp, fc, 512, 0, 256);
    // L5: GEMM5 + sinkhorn fused: A=fc, K=256 -> d_out
    gemm_sink<<<256, 256, 0, stream>>>(fc, 512, 0, 256, 32768ull * 512 - 8,
                                       wt5, 256, bfc, (float*)d_out);
}

// Round 5
// 686.384 us; speedup vs baseline: 1.1810x; 1.1810x over previous
//
#include <hip/hip_runtime.h>
#include <stdint.h>

typedef unsigned short ushort_t;
typedef __attribute__((ext_vector_type(8))) _Float16 half8;   // 8 fp16 = 4 VGPRs
typedef __attribute__((ext_vector_type(2))) __fp16 fp16x2;    // cvt_pkrtz result type
typedef __attribute__((ext_vector_type(4))) float f32x4;
typedef __attribute__((ext_vector_type(4))) unsigned int u32x4;

__device__ __forceinline__ ushort_t h_bits(_Float16 h) {
    union { _Float16 h; ushort_t u; } v; v.h = h; return v.u;
}
__device__ __forceinline__ ushort_t f2h(float x) { return h_bits((_Float16)x); }

// fp16 hi/lo split of a pair via v_cvt_pkrtz (1 instr per 2 elements).
// lo = x - (float)hi is EXACT (Dekker); pair error <= ~2^-21 |x|.
__device__ __forceinline__ void split_pair(float x0, float x1, unsigned& hp, unsigned& lp) {
    fp16x2 h = __builtin_amdgcn_cvt_pkrtz(x0, x1);
    float r0 = x0 - (float)h[0];
    float r1 = x1 - (float)h[1];
    fp16x2 l = __builtin_amdgcn_cvt_pkrtz(r0, r1);
    union { fp16x2 v; unsigned u; } a, b; a.v = h; b.v = l;
    hp = a.u; lp = b.u;
}

__device__ __forceinline__ void gload_lds16(const ushort_t* g, ushort_t* l) {
    __builtin_amdgcn_global_load_lds(
        (const __attribute__((address_space(1))) void*)g,
        (__attribute__((address_space(3))) void*)l, 16, 0, 0);
}

// ---------------------------------------------------------------------------
// prep_all: ALL prep work in ONE launch (block-range dispatch; every sub-task
// uses 256-thread blocks).
//   blocks [0, 8192)        : x_pos -> cat hi/lo + pad zeroing
//   blocks [8192, 8192+1272): 5 weight transposes (tiled 32x32 via LDS)
// Weight layout: out[n*2K + k] = fp16_hi(W[k-shift][n]), out[n*2K+K+k] = lo.
// ---------------------------------------------------------------------------
__global__ void prep_all(const float* __restrict__ seqf,
                         const float* __restrict__ W1t, const float* __restrict__ W1v,
                         const float* __restrict__ W2v, const float* __restrict__ Wfp,
                         const float* __restrict__ Wfc,
                         ushort_t* __restrict__ wt1, ushort_t* __restrict__ wt2,
                         ushort_t* __restrict__ wt3, ushort_t* __restrict__ wt4,
                         ushort_t* __restrict__ wt5, ushort_t* __restrict__ cat)
{
    __shared__ float tile[32][33];
    int b = blockIdx.x;
    if (b < 8192) {
        // ---- prep_cat_pos ----
        long t = (long)b * 256 + threadIdx.x;  // M*64 threads
        long m = t >> 6; int c = (int)(t & 63);
        float x = (c < 4) ? seqf[m * 2352 + 2348 + c] : 0.f;
        _Float16 h = (_Float16)x;
        cat[m * 640 + 256 + c] = h_bits(h);           // hi section cols [256,320)
        cat[m * 640 + 576 + c] = f2h(x - (float)h);   // lo section cols [576,640)
        return;
    }
    b -= 8192;
    // ---- weight transpose tasks ----
    const float* W; ushort_t* out; int Ksrc, Nsrc, K, shift, gx;
    if (b < 40)        { W = W1t; Ksrc = 300;  Nsrc = 128; out = wt1; K = 320;  shift = 0;  gx = 10; }
    else if (b < 1096) { b -= 40;   W = W1v; Ksrc = 2048; Nsrc = 512; out = wt2; K = 2112; shift = 12; gx = 66; }
    else if (b < 1160) { b -= 1096; W = W2v; Ksrc = 512;  Nsrc = 128; out = wt3; K = 512;  shift = 0;  gx = 16; }
    else if (b < 1240) { b -= 1160; W = Wfp; Ksrc = 260;  Nsrc = 256; out = wt4; K = 320;  shift = 0;  gx = 10; }
    else               { b -= 1240; W = Wfc; Ksrc = 256;  Nsrc = 128; out = wt5; K = 256;  shift = 0;  gx = 8;  }
    const int kt = (b % gx) * 32, nt = (b / gx) * 32;
    const int tx = threadIdx.x & 31, ty = threadIdx.x >> 5;   // 32 x 8
#pragma unroll
    for (int r = ty; r < 32; r += 8) {
        int k = kt + r - shift;
        int n = nt + tx;
        tile[r][tx] = (k >= 0 && k < Ksrc && n < Nsrc) ? W[(long)k * Nsrc + n] : 0.f;
    }
    __syncthreads();
#pragma unroll
    for (int r = ty; r < 32; r += 8) {
        int n = nt + r, k = kt + tx;
        if (n < Nsrc && k < K) {
            float w = tile[tx][r];
            _Float16 h = (_Float16)w;
            out[(long)n * 2 * K + k]     = h_bits(h);
            out[(long)n * 2 * K + K + k] = f2h(w - (float)h);
        }
    }
}

// ===========================================================================
// GEMM common: 128x128 tile, BK=64, 4 waves, XOR LDS swizzle,
// 3 MFMA passes per staged slab (Ah·Bh + Al·Bh + Ah·Bl, drop Al·Bl ~2^-21).
// ===========================================================================

// --- Variant A: A is fp32 (seq). COALESCED float4 A-load (8 lanes cover one
// row's 256B) -> cvt_pkrtz split in VGPRs -> XOR-swizzled ds_write_b128.
// Next-slab A loads issued after the staging barrier hide under MFMA.
// Fused dual-GEMM launch: blocks [0,nb1) use param set 1, rest use set 2.
__global__ __launch_bounds__(256, 2)
void gemm_af32(const float* __restrict__ Af, long ldaf, unsigned long long a_maxf,
               int nb1,
               long aoff1, const ushort_t* __restrict__ Bt1, int K1, int ntiles1,
               const float* __restrict__ bias1, ushort_t* __restrict__ out1,
               int ostride1, int hi1, int lo1,
               long aoff2, const ushort_t* __restrict__ Bt2, int K2, int ntiles2,
               const float* __restrict__ bias2, ushort_t* __restrict__ out2,
               int ostride2, int hi2, int lo2)
{
    __shared__ __align__(16) ushort_t Ah[128 * 64];
    __shared__ __align__(16) ushort_t Al[128 * 64];
    __shared__ __align__(16) ushort_t Bh[128 * 64];
    __shared__ __align__(16) ushort_t Bl[128 * 64];

    // param-set select (block-uniform branch by block range)
    long aoff; const ushort_t* Bt; int K, ntiles; const float* bias;
    ushort_t* outb; int ostride, hi_off, lo_off, b;
    if (blockIdx.x < (unsigned)nb1) {
        b = blockIdx.x;
        aoff = aoff1; Bt = Bt1; K = K1; ntiles = ntiles1; bias = bias1;
        outb = out1; ostride = ostride1; hi_off = hi1; lo_off = lo1;
    } else {
        b = blockIdx.x - nb1;
        aoff = aoff2; Bt = Bt2; K = K2; ntiles = ntiles2; bias = bias2;
        outb = out2; ostride = ostride2; hi_off = hi2; lo_off = lo2;
    }

    const int tt = b >> 3;
    const int bx = tt % ntiles;
    const int by = (tt / ntiles) * 8 + (b & 7);

    const int t  = threadIdx.x;
    const int w  = t >> 6, l = t & 63;
    const int wm = w >> 1, wn = w & 1;
    const long m0 = (long)by * 128;
    const int  n0 = bx * 128;
    const long K2s = 2L * K;

    // B staging (global_load_lds, gather-side XOR): chunk c=w*4+i, lane -> row c*8+(l>>3)
    const int lr = l >> 3;
    const int kbg = (l & 7) ^ lr;
    long rowB[4];
#pragma unroll
    for (int i = 0; i < 4; ++i) {
        int c = w * 4 + i;
        rowB[i] = (long)(n0 + c * 8 + lr) * K2s + kbg * 8;
    }

    // A staging cells: cell = i*256 + t -> r = cell>>3 (row), kb = cell&7 (k-block).
    // Lanes 0..7 cover one row's 8 k-blocks = 256B contiguous fp32 -> coalesced.
    unsigned long long agidx[4]; int lofs[4];
#pragma unroll
    for (int i = 0; i < 4; ++i) {
        int cell = i * 256 + t;
        int r = cell >> 3, kb = cell & 7;
        agidx[i] = (unsigned long long)((m0 + r) * ldaf + aoff + kb * 8);
        lofs[i] = r * 64 + ((kb ^ (r & 7)) * 8);   // XOR swizzle on write side
    }

    f32x4 acc[4][4];
#pragma unroll
    for (int i = 0; i < 4; ++i)
#pragma unroll
        for (int j = 0; j < 4; ++j) acc[i][j] = (f32x4){0.f, 0.f, 0.f, 0.f};

    const int col = l & 15, quad = l >> 4;

    float4 va[4][2];
    auto load_va = [&](int k0) {
#pragma unroll
        for (int i = 0; i < 4; ++i) {
            unsigned long long g = agidx[i] + (unsigned long long)k0;
            if (g > a_maxf) g = a_maxf;    // tail overrun -> valid addr (zero weights)
            va[i][0] = *(const float4*)(Af + g);
            va[i][1] = *(const float4*)(Af + g + 4);
        }
    };
    load_va(0);                 // prologue: slab 0 in flight

    for (int k0 = 0; k0 < K; k0 += 64) {
        __syncthreads();            // prev compute done before LDS overwrite
#pragma unroll
        for (int i = 0; i < 4; ++i) {
            const int cb = (w * 4 + i) * 512;
            gload_lds16(Bt + rowB[i] + k0, &Bh[cb]);       // async B while we convert A
            gload_lds16(Bt + rowB[i] + K + k0, &Bl[cb]);
        }
#pragma unroll
        for (int i = 0; i < 4; ++i) {
            unsigned hp[4], lp[4];
            split_pair(va[i][0].x, va[i][0].y, hp[0], lp[0]);
            split_pair(va[i][0].z, va[i][0].w, hp[1], lp[1]);
            split_pair(va[i][1].x, va[i][1].y, hp[2], lp[2]);
            split_pair(va[i][1].z, va[i][1].w, hp[3], lp[3]);
            *(u32x4*)&Ah[lofs[i]] = (u32x4){hp[0], hp[1], hp[2], hp[3]};
            *(u32x4*)&Al[lofs[i]] = (u32x4){lp[0], lp[1], lp[2], lp[3]};
        }
        __syncthreads();            // drains lgkm + vmcnt: staging visible

        if (k0 + 64 < K) load_va(k0 + 64);   // prefetch next A slab under MFMA

#pragma unroll
        for (int p = 0; p < 3; ++p) {
            const ushort_t* Asrc = (p == 1) ? Al : Ah;
            const ushort_t* Bsrc = (p == 2) ? Bl : Bh;
#pragma unroll
            for (int kk = 0; kk < 2; ++kk) {
                half8 a[4], bb[4];
#pragma unroll
                for (int i = 0; i < 4; ++i) {
                    int m = wm * 64 + i * 16 + col;
                    int kbs = (kk * 4 + quad) ^ (m & 7);
                    a[i] = *(const half8*)&Asrc[m * 64 + kbs * 8];
                }
#pragma unroll
                for (int j = 0; j < 4; ++j) {
                    int n = wn * 64 + j * 16 + col;
                    int kbs = (kk * 4 + quad) ^ (n & 7);
                    bb[j] = *(const half8*)&Bsrc[n * 64 + kbs * 8];
                }
#pragma unroll
                for (int i = 0; i < 4; ++i)
#pragma unroll
                    for (int j = 0; j < 4; ++j)
                        acc[i][j] = __builtin_amdgcn_mfma_f32_16x16x32_f16(a[i], bb[j], acc[i][j], 0, 0, 0);
            }
        }
    }

    // epilogue: relu -> hi/lo fp16 (C/D map col=lane&15, row=quad*4+reg)
#pragma unroll
    for (int j = 0; j < 4; ++j) {
        int n = n0 + wn * 64 + j * 16 + col;
        float bv = bias[n];
#pragma unroll
        for (int i = 0; i < 4; ++i) {
#pragma unroll
            for (int r = 0; r < 4; ++r) {
                long m = m0 + wm * 64 + i * 16 + quad * 4 + r;
                float y = fmaxf(acc[i][j][r] + bv, 0.f);
                _Float16 h = (_Float16)y;
                outb[m * (long)ostride + hi_off + n] = h_bits(h);
                outb[m * (long)ostride + lo_off + n] = f2h(y - (float)h);
            }
        }
    }
}

// --- Variant B: A is fp16 hi/lo (activations), global_load_lds staging. Relu.
__global__ __launch_bounds__(256, 2)
void gemm_bt(const ushort_t* __restrict__ A, long lda, long aoff_hi, long aoff_lo,
             unsigned long long a_max,
             const ushort_t* __restrict__ Bt, int K, int ntiles,
             const float* __restrict__ bias,
             ushort_t* __restrict__ outb, int ostride, int hi_off, int lo_off)
{
    __shared__ __align__(16) ushort_t Ah[128 * 64];
    __shared__ __align__(16) ushort_t Al[128 * 64];
    __shared__ __align__(16) ushort_t Bh[128 * 64];
    __shared__ __align__(16) ushort_t Bl[128 * 64];

    const int b = blockIdx.x;
    const int tt = b >> 3;
    const int bx = tt % ntiles;
    const int by = (tt / ntiles) * 8 + (b & 7);

    const int t  = threadIdx.x;
    const int w  = t >> 6, l = t & 63;
    const int wm = w >> 1, wn = w & 1;
    const long m0 = (long)by * 128;
    const int  n0 = bx * 128;
    const long K2 = 2L * K;

    const int lr = l >> 3;
    const int kbg = (l & 7) ^ lr;
    unsigned long long rowA[4]; long rowB[4];
#pragma unroll
    for (int i = 0; i < 4; ++i) {
        int c = w * 4 + i;
        rowA[i] = (unsigned long long)((m0 + c * 8 + lr) * lda + kbg * 8);
        rowB[i] = (long)(n0 + c * 8 + lr) * K2 + kbg * 8;
    }

    f32x4 acc[4][4];
#pragma unroll
    for (int i = 0; i < 4; ++i)
#pragma unroll
        for (int j = 0; j < 4; ++j) acc[i][j] = (f32x4){0.f, 0.f, 0.f, 0.f};

    const int col = l & 15, quad = l >> 4;

    for (int k0 = 0; k0 < K; k0 += 64) {
        __syncthreads();
#pragma unroll
        for (int i = 0; i < 4; ++i) {
            const int cb = (w * 4 + i) * 512;
            unsigned long long ah = rowA[i] + (unsigned long long)(aoff_hi + k0);
            unsigned long long al = rowA[i] + (unsigned long long)(aoff_lo + k0);
            if (ah > a_max) ah = a_max;
            if (al > a_max) al = a_max;
            gload_lds16(A + ah, &Ah[cb]);
            gload_lds16(A + al, &Al[cb]);
            gload_lds16(Bt + rowB[i] + k0, &Bh[cb]);
            gload_lds16(Bt + rowB[i] + K + k0, &Bl[cb]);
        }
        __syncthreads();

#pragma unroll
        for (int p = 0; p < 3; ++p) {
            const ushort_t* Asrc = (p == 1) ? Al : Ah;
            const ushort_t* Bsrc = (p == 2) ? Bl : Bh;
#pragma unroll
            for (int kk = 0; kk < 2; ++kk) {
                half8 a[4], bb[4];
#pragma unroll
                for (int i = 0; i < 4; ++i) {
                    int m = wm * 64 + i * 16 + col;
                    int kbs = (kk * 4 + quad) ^ (m & 7);
                    a[i] = *(const half8*)&Asrc[m * 64 + kbs * 8];
                }
#pragma unroll
                for (int j = 0; j < 4; ++j) {
                    int n = wn * 64 + j * 16 + col;
                    int kbs = (kk * 4 + quad) ^ (n & 7);
                    bb[j] = *(const half8*)&Bsrc[n * 64 + kbs * 8];
                }
#pragma unroll
                for (int i = 0; i < 4; ++i)
#pragma unroll
                    for (int j = 0; j < 4; ++j)
                        acc[i][j] = __builtin_amdgcn_mfma_f32_16x16x32_f16(a[i], bb[j], acc[i][j], 0, 0, 0);
            }
        }
    }

#pragma unroll
    for (int j = 0; j < 4; ++j) {
        int n = n0 + wn * 64 + j * 16 + col;
        float bv = bias[n];
#pragma unroll
        for (int i = 0; i < 4; ++i) {
#pragma unroll
            for (int r = 0; r < 4; ++r) {
                long m = m0 + wm * 64 + i * 16 + quad * 4 + r;
                float y = fmaxf(acc[i][j][r] + bv, 0.f);
                _Float16 h = (_Float16)y;
                outb[m * (long)ostride + hi_off + n] = h_bits(h);
                outb[m * (long)ostride + lo_off + n] = f2h(y - (float)h);
            }
        }
    }
}

// --- Variant C: GEMM5 + sinkhorn fused. One block = one 128x128 M-tile = one
// batch matrix. K-loop as variant B; epilogue writes tanh(z) into the dead
// staging LDS (swizzled col (n+m)&127 -> conflict-free row AND col reads),
// builds register K = exp(z*10), runs 20 sinkhorn iterations on u/v in LDS.
__global__ __launch_bounds__(256, 1)
void gemm_sink(const ushort_t* __restrict__ A, long lda, long aoff_hi, long aoff_lo,
               unsigned long long a_max,
               const ushort_t* __restrict__ Bt, int K,
               const float* __restrict__ bias,
               float* __restrict__ out)
{
    __shared__ __align__(16) unsigned char smem[65536];
    ushort_t* Ah = (ushort_t*)smem;              // 16 KB each
    ushort_t* Al = (ushort_t*)(smem + 16384);
    ushort_t* Bh = (ushort_t*)(smem + 32768);
    ushort_t* Bl = (ushort_t*)(smem + 49152);

    const int b = blockIdx.x;                    // batch index (identity swizzle)
    const int t  = threadIdx.x;
    const int w  = t >> 6, l = t & 63;
    const int wm = w >> 1, wn = w & 1;
    const long m0 = (long)b * 128;
    const long K2 = 2L * K;

    const int lr = l >> 3;
    const int kbg = (l & 7) ^ lr;
    unsigned long long rowA[4]; long rowB[4];
#pragma unroll
    for (int i = 0; i < 4; ++i) {
        int c = w * 4 + i;
        rowA[i] = (unsigned long long)((m0 + c * 8 + lr) * lda + kbg * 8);
        rowB[i] = (long)(c * 8 + lr) * K2 + kbg * 8;
    }

    f32x4 acc[4][4];
#pragma unroll
    for (int i = 0; i < 4; ++i)
#pragma unroll
        for (int j = 0; j < 4; ++j) acc[i][j] = (f32x4){0.f, 0.f, 0.f, 0.f};

    const int col = l & 15, quad = l >> 4;

    for (int k0 = 0; k0 < K; k0 += 64) {
        __syncthreads();
#pragma unroll
        for (int i = 0; i < 4; ++i) {
            const int cb = (w * 4 + i) * 512;
            unsigned long long ah = rowA[i] + (unsigned long long)(aoff_hi + k0);
            unsigned long long al = rowA[i] + (unsigned long long)(aoff_lo + k0);
            if (ah > a_max) ah = a_max;
            if (al > a_max) al = a_max;
            gload_lds16(A + ah, &Ah[cb]);
            gload_lds16(A + al, &Al[cb]);
            gload_lds16(Bt + rowB[i] + k0, &Bh[cb]);
            gload_lds16(Bt + rowB[i] + K + k0, &Bl[cb]);
        }
        __syncthreads();
#pragma unroll
        for (int p = 0; p < 3; ++p) {
            const ushort_t* Asrc = (p == 1) ? Al : Ah;
            const ushort_t* Bsrc = (p == 2) ? Bl : Bh;
#pragma unroll
            for (int kk = 0; kk < 2; ++kk) {
                half8 a[4], bb[4];
#pragma unroll
                for (int i = 0; i < 4; ++i) {
                    int m = wm * 64 + i * 16 + col;
                    int kbs = (kk * 4 + quad) ^ (m & 7);
                    a[i] = *(const half8*)&Asrc[m * 64 + kbs * 8];
                }
#pragma unroll
                for (int j = 0; j < 4; ++j) {
                    int n = wn * 64 + j * 16 + col;
                    int kbs = (kk * 4 + quad) ^ (n & 7);
                    bb[j] = *(const half8*)&Bsrc[n * 64 + kbs * 8];
                }
#pragma unroll
                for (int i = 0; i < 4; ++i)
#pragma unroll
                    for (int j = 0; j < 4; ++j)
                        acc[i][j] = __builtin_amdgcn_mfma_f32_16x16x32_f16(a[i], bb[j], acc[i][j], 0, 0, 0);
            }
        }
    }

    // ---- epilogue: z = tanh(acc + bias) -> swizzled LDS ----
    __syncthreads();                       // LDS dead; reuse as z tile
    float* zs = (float*)smem;              // 128x128 fp32, col stored at (n+m)&127
#pragma unroll
    for (int j = 0; j < 4; ++j) {
        int n = wn * 64 + j * 16 + col;
        float bv = bias[n];
#pragma unroll
        for (int i = 0; i < 4; ++i) {
#pragma unroll
            for (int r = 0; r < 4; ++r) {
                int m = wm * 64 + i * 16 + quad * 4 + r;
                float y = acc[i][j][r] + bv;
                float e = __expf(2.f * y);             // tanh = 1 - 2/(e+1), inf-safe
                zs[m * 128 + ((n + m) & 127)] = 1.f - 2.f / (e + 1.f);
            }
        }
    }
    __syncthreads();

    // ---- sinkhorn: X = diag(u) K diag(v), K register-resident ----
    const int jc = t & 127, h = t >> 7;
    float Kc[64], Kr[64];
#pragma unroll
    for (int s = 0; s < 64; ++s) {         // column copy: K[h+2s][jc]
        int m = h + 2 * s;
        Kc[s] = __expf(zs[m * 128 + ((jc + m) & 127)] * 10.0f);
    }
#pragma unroll
    for (int s = 0; s < 64; ++s) {         // row copy: K[jc][h+2s]
        int n = h + 2 * s;
        Kr[s] = __expf(zs[jc * 128 + ((n + jc) & 127)] * 10.0f);
    }
    __syncthreads();                       // zs dead; carve u/v/P from smem
    float* P = (float*)smem;               // 256 floats
    float* u = P + 256;                    // 128
    float* v = u + 128;                    // 128
    if (t < 128) { u[t] = 1.f; v[t] = 1.f; }
    __syncthreads();

#pragma unroll 1
    for (int it = 0; it < 20; ++it) {
        float p = 0.f;
#pragma unroll
        for (int s = 0; s < 64; ++s) p += u[h + 2 * s] * Kc[s];
        P[t] = p;
        __syncthreads();
        if (t < 128) {
            float T = P[t] + P[t + 128];
            float vv = v[t];
            v[t] = vv / (1e-7f + vv * T);
        }
        __syncthreads();
        p = 0.f;
#pragma unroll
        for (int s = 0; s < 64; ++s) p += v[h + 2 * s] * Kr[s];
        P[t] = p;
        __syncthreads();
        if (t < 128) {
            float R = P[t] + P[t + 128];
            float uu = u[t];
            u[t] = uu / (1e-7f + uu * R);
        }
        __syncthreads();
    }

    const long base = m0 * 128;
#pragma unroll
    for (int s = 0; s < 64; ++s)           // out[(h+2s)*128 + jc] == t + 256s
        out[base + t + 256 * s] = u[h + 2 * s] * Kc[s] * v[jc];
}

// ---------------------------------------------------------------------------
extern "C" void kernel_launch(void* const* d_in, const int* in_sizes, int n_in,
                              void* d_out, int out_size, void* d_ws, size_t ws_size,
                              hipStream_t stream)
{
    const float* seqf = (const float*)d_in[0];
    const float* W1t = (const float*)d_in[1];
    const float* b1t = (const float*)d_in[2];
    const float* W1v = (const float*)d_in[3];
    const float* b1v = (const float*)d_in[4];
    const float* W2v = (const float*)d_in[5];
    const float* b2v = (const float*)d_in[6];
    const float* Wfp = (const float*)d_in[7];
    const float* bfp = (const float*)d_in[8];
    const float* Wfc = (const float*)d_in[9];
    const float* bfc = (const float*)d_in[10];

    char* ws = (char*)d_ws;
    size_t off = 0;
    auto alloc = [&](size_t bytes) { void* p = ws + off; off += (bytes + 255) & ~255ull; return p; };
    ushort_t* wt1 = (ushort_t*)alloc(128ull * 640 * 2);    // W1_txt^T  [h|l] K=320
    ushort_t* wt2 = (ushort_t*)alloc(512ull * 4224 * 2);   // W1_vis^T  [h|l] K=2112, shift12
    ushort_t* wt3 = (ushort_t*)alloc(128ull * 1024 * 2);   // W2_vis^T  [h|l] K=512
    ushort_t* wt4 = (ushort_t*)alloc(256ull * 640 * 2);    // W_fc_pos^T[h|l] K=320
    ushort_t* wt5 = (ushort_t*)alloc(128ull * 512 * 2);    // W_fc^T    [h|l] K=256
    ushort_t* vis = (ushort_t*)alloc(32768ull * 1024 * 2); // x_vis1 [hi(512)|lo(512)]
    ushort_t* cat = (ushort_t*)alloc(32768ull * 640 * 2);  // concat [hi(320)|lo(320)]
    ushort_t* fc  = (ushort_t*)alloc(32768ull * 512 * 2);  // fc_pos [hi(256)|lo(256)]

    // L1: all prep in one launch (8192 cat blocks + 40+1056+64+80+32 transpose)
    prep_all<<<9464, 256, 0, stream>>>(seqf, W1t, W1v, W2v, Wfp, Wfc,
                                       wt1, wt2, wt3, wt4, wt5, cat);

    const unsigned long long seq_maxf = 32768ull * 2352 - 8;   // floats

    // L2: GEMM1 (txt, K=320 -> cat[0,128)h/[320,448)l) + GEMM2 (vis1, K=2112
    // shift12 -> vis) fused into one launch: blocks [0,256) + [256,1280).
    gemm_af32<<<1280, 256, 0, stream>>>(seqf, 2352, seq_maxf, 256,
        /*set1*/ 0,   wt1, 320,  1, b1t, cat, 640, 0, 320,
        /*set2*/ 288, wt2, 2112, 4, b1v, vis, 1024, 0, 512);

    // L3: GEMM3 (vis2): A=vis, K=512 -> cat cols [128,256) hi, [448,576) lo
    gemm_bt<<<256, 256, 0, stream>>>(vis, 1024, 0, 512, 32768ull * 1024 - 8,
                                     wt3, 512, 1, b2v, cat, 640, 128, 448);
    // L4: GEMM4 (fc_pos): A=cat, K=320 -> fc hi|lo
    gemm_bt<<<512, 256, 0, stream>>>(cat, 640, 0, 320, 32768ull * 640 - 8,
                                     wt4, 320, 2, bfp, fc, 512, 0, 256);
    // L5: GEMM5 + sinkhorn fused: A=fc, K=256 -> d_out
    gemm_sink<<<256, 256, 0, stream>>>(fc, 512, 0, 256, 32768ull * 512 - 8,
                                       wt5, 256, bfc, (float*)d_out);
}